// Round 4
// baseline (3361.597 us; speedup 1.0000x reference)
//
#include <hip/hip_runtime.h>

#define D_DIM 256
#define N_TOK 32768
#define K_CB  8192
#define TAU   0.12f
#define ZC_CAP 4096
#define SLABS 32            // rescan: 32 slabs x 256 codes per 64-token group
#define SLABW 256

typedef float    f32x16 __attribute__((ext_vector_type(16)));
typedef float    f32x4  __attribute__((ext_vector_type(4)));
typedef _Float16 f16x8  __attribute__((ext_vector_type(8)));

// ---- workspace layout (bytes) ----
#define OFF_ESQ   0                        // 8192 f32 (32 KB)
#define OFF_CNT   32768                    // int
#define OFF_GDONE 33024                    // 512 i32 (2 KB)
#define OFF_LIST  35072                    // 32768 i32 (128 KB)
#define OFF_FIXB  166144                   // 32768 u64 (256 KB)
#define OFF_EHT   524288                   // 32*8192*8 f16 = 4 MB
#define OFF_ZC    (OFF_EHT + 4194304)      // 4096 tokens x 256 f32 = 4 MB
#define OFF_PBV   (OFF_ZC + 4194304)       // 2*256*128 f32 = 256 KB
#define OFF_PSC   (OFF_PBV + 262144)       // 256 KB
#define OFF_PBK   (OFF_PSC + 262144)       // 256 KB
#define MAXGRP    512
#define WS_NEED   ((size_t)(OFF_PBK + 262144))

#define SMEM_MAIN 65536

// ===========================================================================
// P: eht[c][k][8] = f16 of e[k][8c+j], coalesced stores (lanes k-major ->
// 16B/lane consecutive). esq[k] via LDS reduce. Zeros cnt + gdone.
// ===========================================================================
__global__ __launch_bounds__(256) void eprep_kernel(const float* __restrict__ e,
                                                    short* __restrict__ eht,
                                                    float* __restrict__ esq,
                                                    int* __restrict__ cnt,
                                                    int* __restrict__ gdone) {
  __shared__ float ps[4 * 64];
  const int tid = threadIdx.x;
  const int kk = tid & 63, cc = tid >> 6;     // code-in-group, c-quarter
  const int k = blockIdx.x * 64 + kk;
  if (blockIdx.x == 0) {
    if (tid == 0) *cnt = 0;
    if (tid < 256) { gdone[tid] = 0; gdone[tid + 256] = 0; }
  }
  _Float16* ef = (_Float16*)eht;
  float ss = 0.f;
  #pragma unroll
  for (int c2 = 0; c2 < 8; ++c2) {
    const int c = cc * 8 + c2;
    f32x4 v0 = *(const f32x4*)(e + (size_t)k * D_DIM + c * 8);
    f32x4 v1 = *(const f32x4*)(e + (size_t)k * D_DIM + c * 8 + 4);
    float v[8] = {v0[0], v0[1], v0[2], v0[3], v1[0], v1[1], v1[2], v1[3]};
    f16x8 hv;
    #pragma unroll
    for (int i = 0; i < 8; ++i) {
      ss += v[i] * v[i];
      hv[i] = (_Float16)v[i];               // RNE
    }
    *(f16x8*)(ef + ((size_t)c * K_CB + k) * 8) = hv;   // coalesced over kk
  }
  ps[cc * 64 + kk] = ss;
  __syncthreads();
  if (tid < 64)
    esq[blockIdx.x * 64 + tid] = ps[tid] + ps[64 + tid] + ps[128 + tid] + ps[192 + tid];
}

// ===========================================================================
// Main R4: e-traffic restructure. R3 post-mortem: dur tracks ISSUED e-bytes
// (4 GB @ ~12 TB/s), not MFMA work, not occupancy -> cut issued bytes 4x.
// 512 blocks = 256 token-groups x 2 codebook-halves; 128 tokens/block
// (e-sweep amortized 2x) x 4096 codes (2 MB/block). Duplication-free wave
// map: wave w owns codes [kb+w*64, +64) (f=2 frags), covers ALL 128 tokens
// (j=4), acc[2][4] = 128 AGPR. zs = 64 KB fp16 -> 2 blocks/CU, 4 waves/SIMD.
// Per-token (bv, sec, bk) partials for this k-half go to pbv/psc/pbk;
// vq_merge_kernel merges the two halves.
// ===========================================================================
__global__ __launch_bounds__(512, 4) void vq_main_kernel(
    const float* __restrict__ z, const float* __restrict__ esq_g,
    const short* __restrict__ eht,
    float* __restrict__ pbv, float* __restrict__ psc, int* __restrict__ pbk) {
  extern __shared__ char smem[];
  _Float16* zs = (_Float16*)smem;               // [32 c][128 t][8] f16 = 64 KB

  const int tid  = threadIdx.x;
  const int w    = tid >> 6;          // wave 0..7 = code subgroup (64 codes)
  const int lane = tid & 63;
  const int half = lane >> 5;
  const int l31  = lane & 31;
  const int tg   = blockIdx.x >> 1;   // token group (128 tokens)
  const int kh   = blockIdx.x & 1;    // codebook half (4096 codes)
  const int n0   = tg * 128;
  const _Float16* ef = (const _Float16*)eht;

  // ---- convert -2*z to fp16 directly into LDS (fused zprep) ----
  {
    const int t  = tid & 127;
    const int cb = (tid >> 7) * 8;    // 4 thread-groups x 8 c's
    #pragma unroll
    for (int cc = 0; cc < 8; ++cc) {
      const int c = cb + cc;
      f16x8 hv;
      #pragma unroll
      for (int i = 0; i < 8; ++i)
        hv[i] = (_Float16)(-2.0f * z[(size_t)(c * 8 + i) * N_TOK + n0 + t]); // coalesced over t
      *(f16x8*)(zs + ((size_t)c * 128 + t) * 8) = hv;
    }
  }
  __syncthreads();   // the only barrier before the merge

  float bestv[4] = {3.4e38f, 3.4e38f, 3.4e38f, 3.4e38f};
  float secv[4]  = {3.4e38f, 3.4e38f, 3.4e38f, 3.4e38f};
  int   bestk[4] = {0, 0, 0, 0};

  const int kbase = kh * (K_CB / 2);
  for (int k0 = 0; k0 < K_CB / 2; k0 += 512) {
    const int kb = kbase + k0 + w * 64;

    // ---- acc init = esq broadcast from GLOBAL (L2-hit; no LDS stage) ----
    f32x16 acc[2][4];
    #pragma unroll
    for (int f = 0; f < 2; ++f) {
      const int qb = kb + 32 * f + 4 * half;
      #pragma unroll
      for (int g = 0; g < 4; ++g) {
        f32x4 q = *(const f32x4*)(esq_g + qb + 8 * g);
        #pragma unroll
        for (int r = 0; r < 4; ++r) {
          const float qv = q[r];
          #pragma unroll
          for (int j = 0; j < 4; ++j) acc[f][j][g * 4 + r] = qv;
        }
      }
    }

    #pragma unroll 2
    for (int dc = 0; dc < 16; ++dc) {
      f16x8 a[2], b[4];
      const size_t ebase = ((size_t)(2 * dc + half) * K_CB + kb + l31) * 8;
      a[0] = *(const f16x8*)(ef + ebase);            // global, coalesced 16B/lane
      a[1] = *(const f16x8*)(ef + ebase + 32 * 8);
      const int zb = ((2 * dc + half) * 128 + l31) * 8;
      #pragma unroll
      for (int j = 0; j < 4; ++j)
        b[j] = *(const f16x8*)(zs + zb + j * 32 * 8);
      #pragma unroll
      for (int f = 0; f < 2; ++f)
        #pragma unroll
        for (int j = 0; j < 4; ++j)
          acc[f][j] = __builtin_amdgcn_mfma_f32_32x32x16_f16(a[f], b[j], acc[f][j], 0, 0, 0);
    }

    // epilogue: running best/second per token-group j (k ascending per lane)
    #pragma unroll
    for (int f = 0; f < 2; ++f) {
      const int base = kb + 32 * f + 4 * half;
      #pragma unroll
      for (int g = 0; g < 4; ++g) {
        #pragma unroll
        for (int r = 0; r < 4; ++r) {
          const int reg = g * 4 + r;
          const int kglob = base + 8 * g + r;
          #pragma unroll
          for (int j = 0; j < 4; ++j) {
            const float s = acc[f][j][reg];
            if (s < bestv[j]) { secv[j] = bestv[j]; bestv[j] = s; bestk[j] = kglob; }
            else if (s < secv[j]) secv[j] = s;
          }
        }
      }
    }
  }

  // ---- cross-wave merge: 16 partials per token (8 waves x 2 half-lanes) ----
  __syncthreads();
  float* pv  = (float*)(smem);                  // [16][128]
  int*   pk  = (int*)  (smem + 8192);
  float* ps2 = (float*)(smem + 16384);
  const int slot = w * 2 + half;
  #pragma unroll
  for (int j = 0; j < 4; ++j) {
    const int t = j * 32 + l31;
    pv [slot * 128 + t] = bestv[j];
    pk [slot * 128 + t] = bestk[j];
    ps2[slot * 128 + t] = secv[j];
  }
  __syncthreads();
  if (tid < 128) {
    const int t = tid;
    float bv = pv[t]; int bk = pk[t]; float sc = ps2[t];
    #pragma unroll
    for (int s2 = 1; s2 < 16; ++s2) {
      float v = pv[s2 * 128 + t]; int k2 = pk[s2 * 128 + t]; float s3 = ps2[s2 * 128 + t];
      if (v < bv || (v == bv && k2 < bk)) { sc = fminf(bv, s3); bv = v; bk = k2; }
      else                                { sc = fminf(sc, v); }
    }
    const size_t o = ((size_t)kh * 256 + tg) * 128 + t;
    pbv[o] = bv; psc[o] = sc; pbk[o] = bk;
  }
}

// ===========================================================================
// Merge: combine the two k-half partials per token. Exact global second =
// min(second of winning half, best of losing half). Writes index, flags
// margin<TAU tokens for rescan (+compacts their z into zc), gathers z_q.
// ===========================================================================
__global__ __launch_bounds__(256) void vq_merge_kernel(
    const float* __restrict__ z, const float* __restrict__ e,
    const float* __restrict__ pbv, const float* __restrict__ psc,
    const int* __restrict__ pbk,
    float* __restrict__ out, int* __restrict__ cnt, int* __restrict__ list,
    unsigned long long* __restrict__ fixb, float* __restrict__ zc) {
  __shared__ int fin[128], slo[128];
  const int tid = threadIdx.x;
  const int g = blockIdx.x;              // 256 groups x 128 tokens
  const int n0 = g * 128;
  if (tid < 128) {
    const size_t o0 = ((size_t)g) * 128 + tid;
    const size_t o1 = ((size_t)256 + g) * 128 + tid;
    const float bv0 = pbv[o0], bv1 = pbv[o1];
    const float sc0 = psc[o0], sc1 = psc[o1];
    const int   bk0 = pbk[o0], bk1 = pbk[o1];
    float bv, sc; int bk;
    if (bv0 <= bv1) { bv = bv0; bk = bk0; sc = fminf(sc0, bv1); }  // bk0<bk1 always
    else            { bv = bv1; bk = bk1; sc = fminf(sc1, bv0); }
    fin[tid] = bk;
    int sl = -1;
    const int n = n0 + tid;
    out[(size_t)D_DIM * N_TOK + n] = (float)bk;     // indices as float (exact)
    if (sc - bv < TAU) {                            // flag for exact rescan
      int p = atomicAdd(cnt, 1);
      list[p] = n;
      fixb[n] = 0xFFFFFFFFFFFFFFFFULL;
      if (p < ZC_CAP) sl = p;
    }
    slo[tid] = sl;
  }
  __syncthreads();
  // ---- compact flagged z columns into zc (coalesced source for rescan) ----
  for (int tt = 0; tt < 128; ++tt) {
    const int p = slo[tt];                          // uniform broadcast
    if (p >= 0)
      zc[(size_t)p * 256 + tid] = z[(size_t)tid * N_TOK + n0 + tt];
  }
  // ---- z_q gather: float4 codebook loads, coalesced stores over t ----
  {
    const int t = tid & 127, d0 = tid >> 7;         // d0 0..1
    const int kk = fin[t];
    const f32x4* row = (const f32x4*)(e + (size_t)kk * D_DIM) + d0 * 32;
    #pragma unroll 4
    for (int q = 0; q < 32; ++q) {
      f32x4 v = row[q];
      const int d = d0 * 128 + q * 4;
      out[(size_t)(d + 0) * N_TOK + n0 + t] = v[0];
      out[(size_t)(d + 1) * N_TOK + n0 + t] = v[1];
      out[(size_t)(d + 2) * N_TOK + n0 + t] = v[2];
      out[(size_t)(d + 3) * N_TOK + n0 + t] = v[3];
    }
  }
}

// ===========================================================================
// C2: exact fp32 rescan + finisher. Items = (64-token group) x (256-code
// slab); SLABS=32 items per group. Stage is bank-conflict-free (thread t
// owns token t -> consecutive LDS addresses). zc path coalesced f32x4;
// groups >= ZC_CAP/64 fall back to scattered z reads. atomicMin-merges
// packed (f32bits<<32|k); last-finishing item of a group writes idx + z_q.
// ===========================================================================
__global__ __launch_bounds__(256) void rescan_kernel(
    const float* __restrict__ z, const float* __restrict__ zc,
    const float* __restrict__ e,
    const float* __restrict__ esq, const int* __restrict__ cnt,
    const int* __restrict__ list, unsigned long long* __restrict__ fixb,
    int* __restrict__ gdone, float* __restrict__ out) {
  __shared__ float zs[D_DIM * 64];                 // 64 KB, zs[d*64 + t]
  __shared__ unsigned long long red[16 * 64];      // 8 KB
  __shared__ int fk[64], fn[64], lastflag;
  const int tid = threadIdx.x;
  const int c = *(volatile const int*)cnt;
  if (c == 0) return;
  int groups = (c + 63) >> 6;
  if (groups > MAXGRP) groups = MAXGRP;
  const int items = groups * SLABS;
  const int tx = tid & 15, ty = tid >> 4;

  for (int it = blockIdx.x; it < items; it += gridDim.x) {
    const int g = it / SLABS;
    const int slab = (it % SLABS) * SLABW;
    __syncthreads();                               // protect zs/red reuse
    // ---- stage z columns for this group ----
    if (g < (ZC_CAP >> 6)) {
      // compact path: thread t owns token t -> conflict-free LDS writes
      const int t = tid & 63, seg = tid >> 6;      // seg 0..3 (64 d's each)
      const int idx = g * 64 + t;
      const float* src = zc + (size_t)(idx < c ? idx : c - 1) * 256 + seg * 64;
      #pragma unroll
      for (int r = 0; r < 16; ++r) {
        f32x4 v = *(const f32x4*)(src + r * 4);
        const int d = seg * 64 + r * 4;
        zs[(d + 0) * 64 + t] = v[0];
        zs[(d + 1) * 64 + t] = v[1];
        zs[(d + 2) * 64 + t] = v[2];
        zs[(d + 3) * 64 + t] = v[3];
      }
    } else {
      // overflow fallback: scattered reads from z
      const int t = tid & 63, dq = tid >> 6;       // dq 0..3
      const int idx = g * 64 + t;
      const int n = list[idx < c ? idx : c - 1];
      #pragma unroll 4
      for (int dd = 0; dd < 64; ++dd) {
        const int d = dq * 64 + dd;
        zs[d * 64 + t] = z[(size_t)d * N_TOK + n];
      }
    }
    __syncthreads();

    unsigned long long lmin[4] = {~0ULL, ~0ULL, ~0ULL, ~0ULL};
    #pragma unroll
    for (int k0 = 0; k0 < SLABW; k0 += 64) {
      const f32x4* er[4]; float eqv[4];
      #pragma unroll
      for (int j = 0; j < 4; ++j) {
        int k = slab + k0 + ty + 16 * j;
        er[j] = (const f32x4*)(e + (size_t)k * D_DIM);
        eqv[j] = esq[k];
      }
      float acc[4][4];
      #pragma unroll
      for (int i = 0; i < 4; ++i)
        #pragma unroll
        for (int j = 0; j < 4; ++j) acc[i][j] = 0.f;
      #pragma unroll 4
      for (int d4 = 0; d4 < D_DIM / 4; ++d4) {
        f32x4 ev[4];
        #pragma unroll
        for (int j = 0; j < 4; ++j) ev[j] = er[j][d4];
        #pragma unroll
        for (int dd = 0; dd < 4; ++dd) {
          float zv[4];
          #pragma unroll
          for (int i = 0; i < 4; ++i) zv[i] = zs[(d4 * 4 + dd) * 64 + tx + 16 * i];
          #pragma unroll
          for (int i = 0; i < 4; ++i)
            #pragma unroll
            for (int j = 0; j < 4; ++j) acc[i][j] += zv[i] * ev[j][dd];
        }
      }
      #pragma unroll
      for (int j = 0; j < 4; ++j) {
        const int k = slab + k0 + ty + 16 * j;
        #pragma unroll
        for (int i = 0; i < 4; ++i) {
          float s = eqv[j] - 2.0f * acc[i][j] + 1024.0f;   // bias > 0 for packing
          unsigned long long p =
              ((unsigned long long)__float_as_uint(s) << 32) | (unsigned)k;
          lmin[i] = (p < lmin[i]) ? p : lmin[i];
        }
      }
    }
    #pragma unroll
    for (int i = 0; i < 4; ++i) red[ty * 64 + tx + 16 * i] = lmin[i];
    __syncthreads();
    if (tid < 64) {
      unsigned long long m = red[tid];
      #pragma unroll
      for (int t = 1; t < 16; ++t) {
        unsigned long long v = red[t * 64 + tid];
        m = (v < m) ? v : m;
      }
      const int idx = g * 64 + tid;
      const int n = list[idx < c ? idx : c - 1];
      atomicMin(&fixb[n], m);
    }
    // ---- completion: last item of this group writes outputs ----
    __threadfence();
    __syncthreads();
    if (tid == 0) lastflag = (atomicAdd(&gdone[g], 1) == SLABS - 1) ? 1 : 0;
    __syncthreads();
    if (lastflag) {
      if (tid < 64) {
        const int idx = g * 64 + tid;
        int kres = -1, n = -1;
        if (idx < c) {
          n = list[idx];
          unsigned long long mv = atomicMin(&fixb[n], 0xFFFFFFFFFFFFFFFFULL);
          kres = (int)(unsigned)(mv & 0xFFFFFFFFu);
          out[(size_t)D_DIM * N_TOK + n] = (float)kres;
        }
        fk[tid] = kres; fn[tid] = n;
      }
      __syncthreads();
      {
        const int t = tid & 63, dq = tid >> 6;
        const int kres = fk[t];
        if (kres >= 0) {
          const int n = fn[t];
          const float* row = e + (size_t)kres * D_DIM;
          #pragma unroll 4
          for (int dd = 0; dd < 64; ++dd) {
            const int d = dq * 64 + dd;
            out[(size_t)d * N_TOK + n] = row[d];
          }
        }
      }
    }
  }
}

// ======================= fallback (round-1 fp32 path) =======================
__global__ __launch_bounds__(256) void esq_kernel(const float* __restrict__ e,
                                                  float* __restrict__ esq) {
  const int wave = threadIdx.x >> 6, lane = threadIdx.x & 63;
  const int k = blockIdx.x * 4 + wave;
  const float4* row = (const float4*)(e + (size_t)k * D_DIM);
  float4 v = row[lane];
  float s = v.x*v.x + v.y*v.y + v.z*v.z + v.w*v.w;
  #pragma unroll
  for (int off = 32; off > 0; off >>= 1) s += __shfl_down(s, off, 64);
  if (lane == 0) esq[k] = s;
}

__global__ __launch_bounds__(256) void vq_kernel(const float* __restrict__ z,
                                                 const float* __restrict__ e,
                                                 const float* __restrict__ esq,
                                                 float* __restrict__ out) {
  __shared__ float zs[D_DIM][64];
  const int tid = threadIdx.x, tx = tid & 15, ty = tid >> 4;
  const int n0 = blockIdx.x * 64;
  {
    const int c = tid & 63, d0 = tid >> 6;
    #pragma unroll 4
    for (int d = d0; d < D_DIM; d += 4) zs[d][c] = z[(size_t)d * N_TOK + n0 + c];
  }
  __syncthreads();
  float bestv[4] = {3.4e38f,3.4e38f,3.4e38f,3.4e38f};
  int   besti[4] = {0,0,0,0};
  for (int k0 = 0; k0 < K_CB; k0 += 64) {
    const float4* er[4]; float eqv[4];
    #pragma unroll
    for (int j = 0; j < 4; ++j) {
      int k = k0 + ty + 16 * j;
      er[j] = (const float4*)(e + (size_t)k * D_DIM);
      eqv[j] = esq[k];
    }
    float acc[4][4];
    #pragma unroll
    for (int i = 0; i < 4; ++i)
      #pragma unroll
      for (int j = 0; j < 4; ++j) acc[i][j] = 0.f;
    #pragma unroll 4
    for (int d4 = 0; d4 < D_DIM/4; ++d4) {
      float4 ev[4];
      #pragma unroll
      for (int j = 0; j < 4; ++j) ev[j] = er[j][d4];
      #pragma unroll
      for (int dd = 0; dd < 4; ++dd) {
        float zv[4];
        #pragma unroll
        for (int i = 0; i < 4; ++i) zv[i] = zs[d4*4+dd][tx + 16*i];
        #pragma unroll
        for (int i = 0; i < 4; ++i)
          #pragma unroll
          for (int j = 0; j < 4; ++j) acc[i][j] += zv[i] * ((const float*)&ev[j])[dd];
      }
    }
    #pragma unroll
    for (int j = 0; j < 4; ++j) {
      int k = k0 + ty + 16 * j;
      #pragma unroll
      for (int i = 0; i < 4; ++i) {
        float s = eqv[j] - 2.0f * acc[i][j];
        if (s < bestv[i]) { bestv[i] = s; besti[i] = k; }
      }
    }
  }
  __syncthreads();
  float* lds = &zs[0][0];
  float* vred = lds; int* ired = (int*)lds + 1024; int* fin = (int*)lds + 2048;
  #pragma unroll
  for (int i = 0; i < 4; ++i) {
    int l = tx + 16 * i;
    vred[ty * 64 + l] = bestv[i]; ired[ty * 64 + l] = besti[i];
  }
  __syncthreads();
  if (tid < 64) {
    float bv = vred[tid]; int bi = ired[tid];
    #pragma unroll
    for (int t = 1; t < 16; ++t) {
      float v = vred[t*64+tid]; int ix = ired[t*64+tid];
      if (v < bv || (v == bv && ix < bi)) { bv = v; bi = ix; }
    }
    fin[tid] = bi;
    out[(size_t)D_DIM * N_TOK + n0 + tid] = (float)bi;
  }
  __syncthreads();
  {
    const int l = tid & 63, d0 = tid >> 6;
    const int kk = fin[l];
    const float* row = e + (size_t)kk * D_DIM;
    #pragma unroll 4
    for (int d = d0; d < D_DIM; d += 4) out[(size_t)d * N_TOK + n0 + l] = row[d];
  }
}

extern "C" void kernel_launch(void* const* d_in, const int* in_sizes, int n_in,
                              void* d_out, int out_size, void* d_ws, size_t ws_size,
                              hipStream_t stream) {
  const float* z = (const float*)d_in[0];
  const float* e = (const float*)d_in[1];
  float* out = (float*)d_out;
  char* ws = (char*)d_ws;

  if (ws_size >= WS_NEED) {
    float* esq = (float*)(ws + OFF_ESQ);
    int* cnt = (int*)(ws + OFF_CNT);
    int* gdone = (int*)(ws + OFF_GDONE);
    int* list = (int*)(ws + OFF_LIST);
    unsigned long long* fixb = (unsigned long long*)(ws + OFF_FIXB);
    short* eht = (short*)(ws + OFF_EHT);
    float* zc = (float*)(ws + OFF_ZC);
    float* pbv = (float*)(ws + OFF_PBV);
    float* psc = (float*)(ws + OFF_PSC);
    int*   pbk = (int*)  (ws + OFF_PBK);

    (void)hipFuncSetAttribute((const void*)vq_main_kernel,
                              hipFuncAttributeMaxDynamicSharedMemorySize, SMEM_MAIN);

    eprep_kernel<<<128, 256, 0, stream>>>(e, eht, esq, cnt, gdone);
    vq_main_kernel<<<512, 512, SMEM_MAIN, stream>>>(z, esq, eht, pbv, psc, pbk);
    vq_merge_kernel<<<256, 256, 0, stream>>>(z, e, pbv, psc, pbk,
                                             out, cnt, list, fixb, zc);
    rescan_kernel<<<512, 256, 0, stream>>>(z, zc, e, esq, cnt, list, fixb, gdone, out);
  } else {
    float* esq = (float*)(ws);
    esq_kernel<<<K_CB / 4, 256, 0, stream>>>(e, esq);
    vq_kernel<<<N_TOK / 64, 256, 0, stream>>>(z, e, esq, out);
  }
}

// Round 6
// 347.408 us; speedup vs baseline: 9.6762x; 9.6762x over previous
//
#include <hip/hip_runtime.h>

#define D_DIM 256
#define N_TOK 32768
#define K_CB  8192
#define TAU   0.12f
#define ZC_CAP 4096
#define SLABS 32            // rescan: 32 slabs x 256 codes per 64-token group
#define SLABW 256

typedef float    f32x16 __attribute__((ext_vector_type(16)));
typedef float    f32x4  __attribute__((ext_vector_type(4)));
typedef _Float16 f16x8  __attribute__((ext_vector_type(8)));

// ---- workspace layout (bytes) ----
#define OFF_ESQ   0                        // 8192 f32 (32 KB)
#define OFF_CNT   32768                    // int
#define OFF_GDONE 33024                    // 512 i32 (2 KB)
#define OFF_LIST  35072                    // 32768 i32 (128 KB)
#define OFF_FIXB  166144                   // 32768 u64 (256 KB)
#define OFF_EHT   524288                   // 32*8192*8 f16 = 4 MB
#define OFF_ZC    (OFF_EHT + 4194304)      // 4096 tokens x 256 f32 = 4 MB
#define OFF_PBV   (OFF_ZC + 4194304)       // 2*256*128 f32 = 256 KB
#define OFF_PSC   (OFF_PBV + 262144)       // 256 KB
#define OFF_PBK   (OFF_PSC + 262144)       // 256 KB
#define MAXGRP    512
#define WS_NEED   ((size_t)(OFF_PBK + 262144))

#define SMEM_MAIN 65536

// ===========================================================================
// P: eht[c][k][8] = f16 of e[k][8c+j], coalesced stores (lanes k-major ->
// 16B/lane consecutive). esq[k] via LDS reduce. Zeros cnt + gdone.
// ===========================================================================
__global__ __launch_bounds__(256) void eprep_kernel(const float* __restrict__ e,
                                                    short* __restrict__ eht,
                                                    float* __restrict__ esq,
                                                    int* __restrict__ cnt,
                                                    int* __restrict__ gdone) {
  __shared__ float ps[4 * 64];
  const int tid = threadIdx.x;
  const int kk = tid & 63, cc = tid >> 6;     // code-in-group, c-quarter
  const int k = blockIdx.x * 64 + kk;
  if (blockIdx.x == 0) {
    if (tid == 0) *cnt = 0;
    if (tid < 256) { gdone[tid] = 0; gdone[tid + 256] = 0; }
  }
  _Float16* ef = (_Float16*)eht;
  float ss = 0.f;
  #pragma unroll
  for (int c2 = 0; c2 < 8; ++c2) {
    const int c = cc * 8 + c2;
    f32x4 v0 = *(const f32x4*)(e + (size_t)k * D_DIM + c * 8);
    f32x4 v1 = *(const f32x4*)(e + (size_t)k * D_DIM + c * 8 + 4);
    float v[8] = {v0[0], v0[1], v0[2], v0[3], v1[0], v1[1], v1[2], v1[3]};
    f16x8 hv;
    #pragma unroll
    for (int i = 0; i < 8; ++i) {
      ss += v[i] * v[i];
      hv[i] = (_Float16)v[i];               // RNE
    }
    *(f16x8*)(ef + ((size_t)c * K_CB + k) * 8) = hv;   // coalesced over kk
  }
  ps[cc * 64 + kk] = ss;
  __syncthreads();
  if (tid < 64)
    esq[blockIdx.x * 64 + tid] = ps[tid] + ps[64 + tid] + ps[128 + tid] + ps[192 + tid];
}

// ===========================================================================
// Main R5 (resubmit; R5 bench was an infra failure, no data): R4's dedup
// structure with a register budget that actually fits. R4 post-mortem:
// acc[2][4]=128 + ~50 arch > the 128-reg/wave cap at (512,4) -> 8.2 GB
// scratch spill. Fix: f=1, j=4 -> acc[4]=64 regs (+~55 arch = ~119 <= 128,
// same budget that fit in R3). Wave w owns 32 codes (ONE A-frag, register-
// reused across all 4 token-groups); k0 step = 256 codes. e-reads stay
// duplication-free: 512 blocks x 2 MB = 1 GB issued (R3: 4 GB). kh=bid&1 +
// %8 XCD round-robin => each XCD L2 holds one 2 MB codebook half.
// MFMA:global = 4:1. Partials to pbv/psc/pbk; merged later.
// ===========================================================================
__global__ __launch_bounds__(512, 4) void vq_main_kernel(
    const float* __restrict__ z, const float* __restrict__ esq_g,
    const short* __restrict__ eht,
    float* __restrict__ pbv, float* __restrict__ psc, int* __restrict__ pbk) {
  extern __shared__ char smem[];
  _Float16* zs = (_Float16*)smem;               // [32 c][128 t][8] f16 = 64 KB

  const int tid  = threadIdx.x;
  const int w    = tid >> 6;          // wave 0..7 = code subgroup (32 codes)
  const int lane = tid & 63;
  const int half = lane >> 5;
  const int l31  = lane & 31;
  const int tg   = blockIdx.x >> 1;   // token group (128 tokens)
  const int kh   = blockIdx.x & 1;    // codebook half (4096 codes)
  const int n0   = tg * 128;
  const _Float16* ef = (const _Float16*)eht;

  // ---- convert -2*z to fp16 directly into LDS (fused zprep) ----
  {
    const int t  = tid & 127;
    const int cb = (tid >> 7) * 8;    // 4 thread-groups x 8 c's
    #pragma unroll
    for (int cc = 0; cc < 8; ++cc) {
      const int c = cb + cc;
      f16x8 hv;
      #pragma unroll
      for (int i = 0; i < 8; ++i)
        hv[i] = (_Float16)(-2.0f * z[(size_t)(c * 8 + i) * N_TOK + n0 + t]); // coalesced over t
      *(f16x8*)(zs + ((size_t)c * 128 + t) * 8) = hv;
    }
  }
  __syncthreads();   // the only barrier before the merge

  float bestv[4] = {3.4e38f, 3.4e38f, 3.4e38f, 3.4e38f};
  float secv[4]  = {3.4e38f, 3.4e38f, 3.4e38f, 3.4e38f};
  int   bestk[4] = {0, 0, 0, 0};

  const int kbase = kh * (K_CB / 2);
  for (int k0 = 0; k0 < K_CB / 2; k0 += 256) {
    const int kb = kbase + k0 + w * 32;

    // ---- acc init = esq broadcast from GLOBAL (L2-hit; no LDS stage) ----
    f32x16 acc[4];
    {
      const int qb = kb + 4 * half;
      #pragma unroll
      for (int g = 0; g < 4; ++g) {
        f32x4 q = *(const f32x4*)(esq_g + qb + 8 * g);
        #pragma unroll
        for (int r = 0; r < 4; ++r) {
          const float qv = q[r];
          #pragma unroll
          for (int j = 0; j < 4; ++j) acc[j][g * 4 + r] = qv;
        }
      }
    }

    #pragma unroll 1
    for (int dc = 0; dc < 16; ++dc) {
      f16x8 a, b[4];
      a = *(const f16x8*)(ef + ((size_t)(2 * dc + half) * K_CB + kb + l31) * 8);
      const int zb = ((2 * dc + half) * 128 + l31) * 8;
      #pragma unroll
      for (int j = 0; j < 4; ++j)
        b[j] = *(const f16x8*)(zs + zb + j * 32 * 8);
      #pragma unroll
      for (int j = 0; j < 4; ++j)
        acc[j] = __builtin_amdgcn_mfma_f32_32x32x16_f16(a, b[j], acc[j], 0, 0, 0);
    }

    // epilogue: running best/second per token-group j (k ascending per lane)
    {
      const int base = kb + 4 * half;
      #pragma unroll
      for (int g = 0; g < 4; ++g) {
        #pragma unroll
        for (int r = 0; r < 4; ++r) {
          const int reg = g * 4 + r;
          const int kglob = base + 8 * g + r;
          #pragma unroll
          for (int j = 0; j < 4; ++j) {
            const float s = acc[j][reg];
            if (s < bestv[j]) { secv[j] = bestv[j]; bestv[j] = s; bestk[j] = kglob; }
            else if (s < secv[j]) secv[j] = s;
          }
        }
      }
    }
  }

  // ---- cross-wave merge: 16 partials per token (8 waves x 2 half-lanes) ----
  __syncthreads();
  float* pv  = (float*)(smem);                  // [16][128]
  int*   pk  = (int*)  (smem + 8192);
  float* ps2 = (float*)(smem + 16384);
  const int slot = w * 2 + half;
  #pragma unroll
  for (int j = 0; j < 4; ++j) {
    const int t = j * 32 + l31;
    pv [slot * 128 + t] = bestv[j];
    pk [slot * 128 + t] = bestk[j];
    ps2[slot * 128 + t] = secv[j];
  }
  __syncthreads();
  if (tid < 128) {
    const int t = tid;
    float bv = pv[t]; int bk = pk[t]; float sc = ps2[t];
    #pragma unroll
    for (int s2 = 1; s2 < 16; ++s2) {
      float v = pv[s2 * 128 + t]; int k2 = pk[s2 * 128 + t]; float s3 = ps2[s2 * 128 + t];
      if (v < bv || (v == bv && k2 < bk)) { sc = fminf(bv, s3); bv = v; bk = k2; }
      else                                { sc = fminf(sc, v); }
    }
    const size_t o = ((size_t)kh * 256 + tg) * 128 + t;
    pbv[o] = bv; psc[o] = sc; pbk[o] = bk;
  }
}

// ===========================================================================
// Merge: combine the two k-half partials per token. Exact global second =
// min(second of winning half, best of losing half). Writes index, flags
// margin<TAU tokens for rescan (+compacts their z into zc), gathers z_q.
// ===========================================================================
__global__ __launch_bounds__(256) void vq_merge_kernel(
    const float* __restrict__ z, const float* __restrict__ e,
    const float* __restrict__ pbv, const float* __restrict__ psc,
    const int* __restrict__ pbk,
    float* __restrict__ out, int* __restrict__ cnt, int* __restrict__ list,
    unsigned long long* __restrict__ fixb, float* __restrict__ zc) {
  __shared__ int fin[128], slo[128];
  const int tid = threadIdx.x;
  const int g = blockIdx.x;              // 256 groups x 128 tokens
  const int n0 = g * 128;
  if (tid < 128) {
    const size_t o0 = ((size_t)g) * 128 + tid;
    const size_t o1 = ((size_t)256 + g) * 128 + tid;
    const float bv0 = pbv[o0], bv1 = pbv[o1];
    const float sc0 = psc[o0], sc1 = psc[o1];
    const int   bk0 = pbk[o0], bk1 = pbk[o1];
    float bv, sc; int bk;
    if (bv0 <= bv1) { bv = bv0; bk = bk0; sc = fminf(sc0, bv1); }  // bk0<bk1 always
    else            { bv = bv1; bk = bk1; sc = fminf(sc1, bv0); }
    fin[tid] = bk;
    int sl = -1;
    const int n = n0 + tid;
    out[(size_t)D_DIM * N_TOK + n] = (float)bk;     // indices as float (exact)
    if (sc - bv < TAU) {                            // flag for exact rescan
      int p = atomicAdd(cnt, 1);
      list[p] = n;
      fixb[n] = 0xFFFFFFFFFFFFFFFFULL;
      if (p < ZC_CAP) sl = p;
    }
    slo[tid] = sl;
  }
  __syncthreads();
  // ---- compact flagged z columns into zc (coalesced source for rescan) ----
  for (int tt = 0; tt < 128; ++tt) {
    const int p = slo[tt];                          // uniform broadcast
    if (p >= 0)
      zc[(size_t)p * 256 + tid] = z[(size_t)tid * N_TOK + n0 + tt];
  }
  // ---- z_q gather: float4 codebook loads, coalesced stores over t ----
  {
    const int t = tid & 127, d0 = tid >> 7;         // d0 0..1
    const int kk = fin[t];
    const f32x4* row = (const f32x4*)(e + (size_t)kk * D_DIM) + d0 * 32;
    #pragma unroll 4
    for (int q = 0; q < 32; ++q) {
      f32x4 v = row[q];
      const int d = d0 * 128 + q * 4;
      out[(size_t)(d + 0) * N_TOK + n0 + t] = v[0];
      out[(size_t)(d + 1) * N_TOK + n0 + t] = v[1];
      out[(size_t)(d + 2) * N_TOK + n0 + t] = v[2];
      out[(size_t)(d + 3) * N_TOK + n0 + t] = v[3];
    }
  }
}

// ===========================================================================
// C2: exact fp32 rescan + finisher. Items = (64-token group) x (256-code
// slab); SLABS=32 items per group. Stage is bank-conflict-free (thread t
// owns token t -> consecutive LDS addresses). zc path coalesced f32x4;
// groups >= ZC_CAP/64 fall back to scattered z reads. atomicMin-merges
// packed (f32bits<<32|k); last-finishing item of a group writes idx + z_q.
// ===========================================================================
__global__ __launch_bounds__(256) void rescan_kernel(
    const float* __restrict__ z, const float* __restrict__ zc,
    const float* __restrict__ e,
    const float* __restrict__ esq, const int* __restrict__ cnt,
    const int* __restrict__ list, unsigned long long* __restrict__ fixb,
    int* __restrict__ gdone, float* __restrict__ out) {
  __shared__ float zs[D_DIM * 64];                 // 64 KB, zs[d*64 + t]
  __shared__ unsigned long long red[16 * 64];      // 8 KB
  __shared__ int fk[64], fn[64], lastflag;
  const int tid = threadIdx.x;
  const int c = *(volatile const int*)cnt;
  if (c == 0) return;
  int groups = (c + 63) >> 6;
  if (groups > MAXGRP) groups = MAXGRP;
  const int items = groups * SLABS;
  const int tx = tid & 15, ty = tid >> 4;

  for (int it = blockIdx.x; it < items; it += gridDim.x) {
    const int g = it / SLABS;
    const int slab = (it % SLABS) * SLABW;
    __syncthreads();                               // protect zs/red reuse
    // ---- stage z columns for this group ----
    if (g < (ZC_CAP >> 6)) {
      // compact path: thread t owns token t -> conflict-free LDS writes
      const int t = tid & 63, seg = tid >> 6;      // seg 0..3 (64 d's each)
      const int idx = g * 64 + t;
      const float* src = zc + (size_t)(idx < c ? idx : c - 1) * 256 + seg * 64;
      #pragma unroll
      for (int r = 0; r < 16; ++r) {
        f32x4 v = *(const f32x4*)(src + r * 4);
        const int d = seg * 64 + r * 4;
        zs[(d + 0) * 64 + t] = v[0];
        zs[(d + 1) * 64 + t] = v[1];
        zs[(d + 2) * 64 + t] = v[2];
        zs[(d + 3) * 64 + t] = v[3];
      }
    } else {
      // overflow fallback: scattered reads from z
      const int t = tid & 63, dq = tid >> 6;       // dq 0..3
      const int idx = g * 64 + t;
      const int n = list[idx < c ? idx : c - 1];
      #pragma unroll 4
      for (int dd = 0; dd < 64; ++dd) {
        const int d = dq * 64 + dd;
        zs[d * 64 + t] = z[(size_t)d * N_TOK + n];
      }
    }
    __syncthreads();

    unsigned long long lmin[4] = {~0ULL, ~0ULL, ~0ULL, ~0ULL};
    #pragma unroll
    for (int k0 = 0; k0 < SLABW; k0 += 64) {
      const f32x4* er[4]; float eqv[4];
      #pragma unroll
      for (int j = 0; j < 4; ++j) {
        int k = slab + k0 + ty + 16 * j;
        er[j] = (const f32x4*)(e + (size_t)k * D_DIM);
        eqv[j] = esq[k];
      }
      float acc[4][4];
      #pragma unroll
      for (int i = 0; i < 4; ++i)
        #pragma unroll
        for (int j = 0; j < 4; ++j) acc[i][j] = 0.f;
      #pragma unroll 4
      for (int d4 = 0; d4 < D_DIM / 4; ++d4) {
        f32x4 ev[4];
        #pragma unroll
        for (int j = 0; j < 4; ++j) ev[j] = er[j][d4];
        #pragma unroll
        for (int dd = 0; dd < 4; ++dd) {
          float zv[4];
          #pragma unroll
          for (int i = 0; i < 4; ++i) zv[i] = zs[(d4 * 4 + dd) * 64 + tx + 16 * i];
          #pragma unroll
          for (int i = 0; i < 4; ++i)
            #pragma unroll
            for (int j = 0; j < 4; ++j) acc[i][j] += zv[i] * ev[j][dd];
        }
      }
      #pragma unroll
      for (int j = 0; j < 4; ++j) {
        const int k = slab + k0 + ty + 16 * j;
        #pragma unroll
        for (int i = 0; i < 4; ++i) {
          float s = eqv[j] - 2.0f * acc[i][j] + 1024.0f;   // bias > 0 for packing
          unsigned long long p =
              ((unsigned long long)__float_as_uint(s) << 32) | (unsigned)k;
          lmin[i] = (p < lmin[i]) ? p : lmin[i];
        }
      }
    }
    #pragma unroll
    for (int i = 0; i < 4; ++i) red[ty * 64 + tx + 16 * i] = lmin[i];
    __syncthreads();
    if (tid < 64) {
      unsigned long long m = red[tid];
      #pragma unroll
      for (int t = 1; t < 16; ++t) {
        unsigned long long v = red[t * 64 + tid];
        m = (v < m) ? v : m;
      }
      const int idx = g * 64 + tid;
      const int n = list[idx < c ? idx : c - 1];
      atomicMin(&fixb[n], m);
    }
    // ---- completion: last item of this group writes outputs ----
    __threadfence();
    __syncthreads();
    if (tid == 0) lastflag = (atomicAdd(&gdone[g], 1) == SLABS - 1) ? 1 : 0;
    __syncthreads();
    if (lastflag) {
      if (tid < 64) {
        const int idx = g * 64 + tid;
        int kres = -1, n = -1;
        if (idx < c) {
          n = list[idx];
          unsigned long long mv = atomicMin(&fixb[n], 0xFFFFFFFFFFFFFFFFULL);
          kres = (int)(unsigned)(mv & 0xFFFFFFFFu);
          out[(size_t)D_DIM * N_TOK + n] = (float)kres;
        }
        fk[tid] = kres; fn[tid] = n;
      }
      __syncthreads();
      {
        const int t = tid & 63, dq = tid >> 6;
        const int kres = fk[t];
        if (kres >= 0) {
          const int n = fn[t];
          const float* row = e + (size_t)kres * D_DIM;
          #pragma unroll 4
          for (int dd = 0; dd < 64; ++dd) {
            const int d = dq * 64 + dd;
            out[(size_t)d * N_TOK + n] = row[d];
          }
        }
      }
    }
  }
}

// ======================= fallback (round-1 fp32 path) =======================
__global__ __launch_bounds__(256) void esq_kernel(const float* __restrict__ e,
                                                  float* __restrict__ esq) {
  const int wave = threadIdx.x >> 6, lane = threadIdx.x & 63;
  const int k = blockIdx.x * 4 + wave;
  const float4* row = (const float4*)(e + (size_t)k * D_DIM);
  float4 v = row[lane];
  float s = v.x*v.x + v.y*v.y + v.z*v.z + v.w*v.w;
  #pragma unroll
  for (int off = 32; off > 0; off >>= 1) s += __shfl_down(s, off, 64);
  if (lane == 0) esq[k] = s;
}

__global__ __launch_bounds__(256) void vq_kernel(const float* __restrict__ z,
                                                 const float* __restrict__ e,
                                                 const float* __restrict__ esq,
                                                 float* __restrict__ out) {
  __shared__ float zs[D_DIM][64];
  const int tid = threadIdx.x, tx = tid & 15, ty = tid >> 4;
  const int n0 = blockIdx.x * 64;
  {
    const int c = tid & 63, d0 = tid >> 6;
    #pragma unroll 4
    for (int d = d0; d < D_DIM; d += 4) zs[d][c] = z[(size_t)d * N_TOK + n0 + c];
  }
  __syncthreads();
  float bestv[4] = {3.4e38f,3.4e38f,3.4e38f,3.4e38f};
  int   besti[4] = {0,0,0,0};
  for (int k0 = 0; k0 < K_CB; k0 += 64) {
    const float4* er[4]; float eqv[4];
    #pragma unroll
    for (int j = 0; j < 4; ++j) {
      int k = k0 + ty + 16 * j;
      er[j] = (const float4*)(e + (size_t)k * D_DIM);
      eqv[j] = esq[k];
    }
    float acc[4][4];
    #pragma unroll
    for (int i = 0; i < 4; ++i)
      #pragma unroll
      for (int j = 0; j < 4; ++j) acc[i][j] = 0.f;
    #pragma unroll 4
    for (int d4 = 0; d4 < D_DIM/4; ++d4) {
      float4 ev[4];
      #pragma unroll
      for (int j = 0; j < 4; ++j) ev[j] = er[j][d4];
      #pragma unroll
      for (int dd = 0; dd < 4; ++dd) {
        float zv[4];
        #pragma unroll
        for (int i = 0; i < 4; ++i) zv[i] = zs[d4*4+dd][tx + 16*i];
        #pragma unroll
        for (int i = 0; i < 4; ++i)
          #pragma unroll
          for (int j = 0; j < 4; ++j) acc[i][j] += zv[i] * ((const float*)&ev[j])[dd];
      }
    }
    #pragma unroll
    for (int j = 0; j < 4; ++j) {
      int k = k0 + ty + 16 * j;
      #pragma unroll
      for (int i = 0; i < 4; ++i) {
        float s = eqv[j] - 2.0f * acc[i][j];
        if (s < bestv[i]) { bestv[i] = s; besti[i] = k; }
      }
    }
  }
  __syncthreads();
  float* lds = &zs[0][0];
  float* vred = lds; int* ired = (int*)lds + 1024; int* fin = (int*)lds + 2048;
  #pragma unroll
  for (int i = 0; i < 4; ++i) {
    int l = tx + 16 * i;
    vred[ty * 64 + l] = bestv[i]; ired[ty * 64 + l] = besti[i];
  }
  __syncthreads();
  if (tid < 64) {
    float bv = vred[tid]; int bi = ired[tid];
    #pragma unroll
    for (int t = 1; t < 16; ++t) {
      float v = vred[t*64+tid]; int ix = ired[t*64+tid];
      if (v < bv || (v == bv && ix < bi)) { bv = v; bi = ix; }
    }
    fin[tid] = bi;
    out[(size_t)D_DIM * N_TOK + n0 + tid] = (float)bi;
  }
  __syncthreads();
  {
    const int l = tid & 63, d0 = tid >> 6;
    const int kk = fin[l];
    const float* row = e + (size_t)kk * D_DIM;
    #pragma unroll 4
    for (int d = d0; d < D_DIM; d += 4) out[(size_t)d * N_TOK + n0 + l] = row[d];
  }
}

extern "C" void kernel_launch(void* const* d_in, const int* in_sizes, int n_in,
                              void* d_out, int out_size, void* d_ws, size_t ws_size,
                              hipStream_t stream) {
  const float* z = (const float*)d_in[0];
  const float* e = (const float*)d_in[1];
  float* out = (float*)d_out;
  char* ws = (char*)d_ws;

  if (ws_size >= WS_NEED) {
    float* esq = (float*)(ws + OFF_ESQ);
    int* cnt = (int*)(ws + OFF_CNT);
    int* gdone = (int*)(ws + OFF_GDONE);
    int* list = (int*)(ws + OFF_LIST);
    unsigned long long* fixb = (unsigned long long*)(ws + OFF_FIXB);
    short* eht = (short*)(ws + OFF_EHT);
    float* zc = (float*)(ws + OFF_ZC);
    float* pbv = (float*)(ws + OFF_PBV);
    float* psc = (float*)(ws + OFF_PSC);
    int*   pbk = (int*)  (ws + OFF_PBK);

    (void)hipFuncSetAttribute((const void*)vq_main_kernel,
                              hipFuncAttributeMaxDynamicSharedMemorySize, SMEM_MAIN);

    eprep_kernel<<<128, 256, 0, stream>>>(e, eht, esq, cnt, gdone);
    vq_main_kernel<<<512, 512, SMEM_MAIN, stream>>>(z, esq, eht, pbv, psc, pbk);
    vq_merge_kernel<<<256, 256, 0, stream>>>(z, e, pbv, psc, pbk,
                                             out, cnt, list, fixb, zc);
    rescan_kernel<<<512, 256, 0, stream>>>(z, zc, e, esq, cnt, list, fixb, gdone, out);
  } else {
    float* esq = (float*)(ws);
    esq_kernel<<<K_CB / 4, 256, 0, stream>>>(e, esq);
    vq_kernel<<<N_TOK / 64, 256, 0, stream>>>(z, e, esq, out);
  }
}

// Round 7
// 340.454 us; speedup vs baseline: 9.8739x; 1.0204x over previous
//
#include <hip/hip_runtime.h>

#define D_DIM 256
#define N_TOK 32768
#define K_CB  8192
#define TAU   0.12f
#define ZC_CAP 4096
#define SLABS 32            // rescan: 32 slabs x 256 codes per 64-token group
#define SLABW 256

typedef float    f32x16 __attribute__((ext_vector_type(16)));
typedef float    f32x4  __attribute__((ext_vector_type(4)));
typedef _Float16 f16x8  __attribute__((ext_vector_type(8)));

// ---- workspace layout (bytes) ----
#define OFF_ESQ   0                        // 8192 f32 (32 KB)
#define OFF_CNT   32768                    // int
#define OFF_GDONE 33024                    // 512 i32 (2 KB)
#define OFF_LIST  35072                    // 32768 i32 (128 KB)
#define OFF_FIXB  166144                   // 32768 u64 (256 KB)
#define OFF_EHT   524288                   // 32*8192*8 f16 = 4 MB
#define OFF_ZC    (OFF_EHT + 4194304)      // 4096 tokens x 256 f32 = 4 MB
#define MAXGRP    512
#define WS_NEED   ((size_t)(OFF_ZC + 4194304))

#define SMEM_MAIN 65536

// ===========================================================================
// P: eht[c][k][8] = f16 of e[k][8c+j], coalesced stores (lanes k-major ->
// 16B/lane consecutive). esq[k] via LDS reduce. Zeros cnt + gdone.
// ===========================================================================
__global__ __launch_bounds__(256) void eprep_kernel(const float* __restrict__ e,
                                                    short* __restrict__ eht,
                                                    float* __restrict__ esq,
                                                    int* __restrict__ cnt,
                                                    int* __restrict__ gdone) {
  __shared__ float ps[4 * 64];
  const int tid = threadIdx.x;
  const int kk = tid & 63, cc = tid >> 6;     // code-in-group, c-quarter
  const int k = blockIdx.x * 64 + kk;
  if (blockIdx.x == 0) {
    if (tid == 0) *cnt = 0;
    if (tid < 256) { gdone[tid] = 0; gdone[tid + 256] = 0; }
  }
  _Float16* ef = (_Float16*)eht;
  float ss = 0.f;
  #pragma unroll
  for (int c2 = 0; c2 < 8; ++c2) {
    const int c = cc * 8 + c2;
    f32x4 v0 = *(const f32x4*)(e + (size_t)k * D_DIM + c * 8);
    f32x4 v1 = *(const f32x4*)(e + (size_t)k * D_DIM + c * 8 + 4);
    float v[8] = {v0[0], v0[1], v0[2], v0[3], v1[0], v1[1], v1[2], v1[3]};
    f16x8 hv;
    #pragma unroll
    for (int i = 0; i < 8; ++i) {
      ss += v[i] * v[i];
      hv[i] = (_Float16)v[i];               // RNE
    }
    *(f16x8*)(ef + ((size_t)c * K_CB + k) * 8) = hv;   // coalesced over kk
  }
  ps[cc * 64 + kk] = ss;
  __syncthreads();
  if (tid < 64)
    esq[blockIdx.x * 64 + tid] = ps[tid] + ps[64 + tid] + ps[128 + tid] + ps[192 + tid];
}

// ===========================================================================
// Main R7: fused single-pass screen. R6 post-mortem: vq_main is LDS-operand
// bound (~82us floor: 1 ds_read_b128 z-frag per MFMA) at ~50% pipe
// efficiency (unroll-1 dc loop serializes a-load -> b-loads -> MFMA), and
// the kh split costs a merge kernel + partials roundtrip (~175us non-main).
// Changes: (a) 256 blocks x 1024 thr (16 waves, still 4/SIMD); each block
// scans ALL 8192 codes for its 128 tokens -> no kh split, merge fused
// in-block (32-slot LDS reduce), index/flag/zc/z_q tail inlined; issued
// e-bytes stay 1 GB (dedup preserved; lockstep k0 sweep keeps the hot
// window L2-resident). (b) dc loop unroll 2 (R3's proven 52-VGPR config)
// for cross-iteration load/MFMA overlap. Wave w owns 32 codes per 512-code
// k0-step; j=4 token-groups; acc[4] = 64 AGPR.
// ===========================================================================
__global__ __launch_bounds__(1024, 4) void vq_main_kernel(
    const float* __restrict__ z, const float* __restrict__ e,
    const float* __restrict__ esq_g,
    const short* __restrict__ eht,
    float* __restrict__ out,
    int* __restrict__ cnt, int* __restrict__ list,
    unsigned long long* __restrict__ fixb, float* __restrict__ zc) {
  extern __shared__ char smem[];
  _Float16* zs = (_Float16*)smem;               // [32 c][128 t][8] f16 = 64 KB
  __shared__ int fin[128], slo[128];

  const int tid  = threadIdx.x;
  const int w    = tid >> 6;          // wave 0..15 = code subgroup (32 codes)
  const int lane = tid & 63;
  const int half = lane >> 5;
  const int l31  = lane & 31;
  const int n0   = blockIdx.x * 128;  // 256 blocks x 128 tokens
  const _Float16* ef = (const _Float16*)eht;

  // ---- convert -2*z to fp16 directly into LDS (fused zprep) ----
  {
    const int t  = tid & 127;
    const int cb = (tid >> 7) * 4;    // 8 thread-groups x 4 c's
    #pragma unroll
    for (int cc = 0; cc < 4; ++cc) {
      const int c = cb + cc;
      f16x8 hv;
      #pragma unroll
      for (int i = 0; i < 8; ++i)
        hv[i] = (_Float16)(-2.0f * z[(size_t)(c * 8 + i) * N_TOK + n0 + t]); // coalesced over t
      *(f16x8*)(zs + ((size_t)c * 128 + t) * 8) = hv;
    }
  }
  __syncthreads();   // the only barrier before the merge

  float bestv[4] = {3.4e38f, 3.4e38f, 3.4e38f, 3.4e38f};
  float secv[4]  = {3.4e38f, 3.4e38f, 3.4e38f, 3.4e38f};
  int   bestk[4] = {0, 0, 0, 0};

  for (int k0 = 0; k0 < K_CB; k0 += 512) {
    const int kb = k0 + w * 32;

    // ---- acc init = esq broadcast from GLOBAL (L2-hit; no LDS stage) ----
    f32x16 acc[4];
    {
      const int qb = kb + 4 * half;
      #pragma unroll
      for (int g = 0; g < 4; ++g) {
        f32x4 q = *(const f32x4*)(esq_g + qb + 8 * g);
        #pragma unroll
        for (int r = 0; r < 4; ++r) {
          const float qv = q[r];
          #pragma unroll
          for (int j = 0; j < 4; ++j) acc[j][g * 4 + r] = qv;
        }
      }
    }

    #pragma unroll 2
    for (int dc = 0; dc < 16; ++dc) {
      f16x8 a, b[4];
      a = *(const f16x8*)(ef + ((size_t)(2 * dc + half) * K_CB + kb + l31) * 8);
      const int zb = ((2 * dc + half) * 128 + l31) * 8;
      #pragma unroll
      for (int j = 0; j < 4; ++j)
        b[j] = *(const f16x8*)(zs + zb + j * 32 * 8);
      #pragma unroll
      for (int j = 0; j < 4; ++j)
        acc[j] = __builtin_amdgcn_mfma_f32_32x32x16_f16(a, b[j], acc[j], 0, 0, 0);
    }

    // epilogue: running best/second per token-group j (k ascending per lane)
    {
      const int base = kb + 4 * half;
      #pragma unroll
      for (int g = 0; g < 4; ++g) {
        #pragma unroll
        for (int r = 0; r < 4; ++r) {
          const int reg = g * 4 + r;
          const int kglob = base + 8 * g + r;
          #pragma unroll
          for (int j = 0; j < 4; ++j) {
            const float s = acc[j][reg];
            if (s < bestv[j]) { secv[j] = bestv[j]; bestv[j] = s; bestk[j] = kglob; }
            else if (s < secv[j]) secv[j] = s;
          }
        }
      }
    }
  }

  // ---- cross-wave merge: 32 partials per token (16 waves x 2 half-lanes) ----
  __syncthreads();
  float* pv  = (float*)(smem);                  // [32][128] = 16 KB
  int*   pk  = (int*)  (smem + 16384);
  float* ps2 = (float*)(smem + 32768);
  const int slot = w * 2 + half;
  #pragma unroll
  for (int j = 0; j < 4; ++j) {
    const int t = j * 32 + l31;
    pv [slot * 128 + t] = bestv[j];
    pk [slot * 128 + t] = bestk[j];
    ps2[slot * 128 + t] = secv[j];
  }
  __syncthreads();
  if (tid < 128) {
    const int t = tid;
    float bv = pv[t]; int bk = pk[t]; float sc = ps2[t];
    #pragma unroll
    for (int s2 = 1; s2 < 32; ++s2) {
      float v = pv[s2 * 128 + t]; int k2 = pk[s2 * 128 + t]; float s3 = ps2[s2 * 128 + t];
      if (v < bv || (v == bv && k2 < bk)) { sc = fminf(bv, s3); bv = v; bk = k2; }
      else                                { sc = fminf(sc, v); }
    }
    fin[t] = bk;
    int sl = -1;
    const int n = n0 + t;
    out[(size_t)D_DIM * N_TOK + n] = (float)bk;     // indices as float (exact)
    if (sc - bv < TAU) {                            // flag for exact rescan
      int p = atomicAdd(cnt, 1);
      list[p] = n;
      fixb[n] = 0xFFFFFFFFFFFFFFFFULL;
      if (p < ZC_CAP) sl = p;
    }
    slo[t] = sl;
  }
  __syncthreads();

  // ---- compact flagged z columns into zc (coalesced source for rescan) ----
  for (int tt = 0; tt < 128; ++tt) {
    const int p = slo[tt];                          // uniform broadcast
    if (p >= 0 && tid < 256)
      zc[(size_t)p * 256 + tid] = z[(size_t)tid * N_TOK + n0 + tt];
  }

  // ---- z_q gather: float4 codebook loads, coalesced stores over t ----
  {
    const int t = tid & 127, d0 = tid >> 7;         // d0 0..7
    const int kk = fin[t];
    const f32x4* row = (const f32x4*)(e + (size_t)kk * D_DIM) + d0 * 8;
    #pragma unroll 4
    for (int q = 0; q < 8; ++q) {
      f32x4 v = row[q];
      const int d = d0 * 32 + q * 4;
      out[(size_t)(d + 0) * N_TOK + n0 + t] = v[0];
      out[(size_t)(d + 1) * N_TOK + n0 + t] = v[1];
      out[(size_t)(d + 2) * N_TOK + n0 + t] = v[2];
      out[(size_t)(d + 3) * N_TOK + n0 + t] = v[3];
    }
  }
}

// ===========================================================================
// C2: exact fp32 rescan + finisher. Items = (64-token group) x (256-code
// slab); SLABS=32 items per group. Stage is bank-conflict-free (thread t
// owns token t -> consecutive LDS addresses). zc path coalesced f32x4;
// groups >= ZC_CAP/64 fall back to scattered z reads. atomicMin-merges
// packed (f32bits<<32|k); last-finishing item of a group writes idx + z_q.
// ===========================================================================
__global__ __launch_bounds__(256) void rescan_kernel(
    const float* __restrict__ z, const float* __restrict__ zc,
    const float* __restrict__ e,
    const float* __restrict__ esq, const int* __restrict__ cnt,
    const int* __restrict__ list, unsigned long long* __restrict__ fixb,
    int* __restrict__ gdone, float* __restrict__ out) {
  __shared__ float zs[D_DIM * 64];                 // 64 KB, zs[d*64 + t]
  __shared__ unsigned long long red[16 * 64];      // 8 KB
  __shared__ int fk[64], fn[64], lastflag;
  const int tid = threadIdx.x;
  const int c = *(volatile const int*)cnt;
  if (c == 0) return;
  int groups = (c + 63) >> 6;
  if (groups > MAXGRP) groups = MAXGRP;
  const int items = groups * SLABS;
  const int tx = tid & 15, ty = tid >> 4;

  for (int it = blockIdx.x; it < items; it += gridDim.x) {
    const int g = it / SLABS;
    const int slab = (it % SLABS) * SLABW;
    __syncthreads();                               // protect zs/red reuse
    // ---- stage z columns for this group ----
    if (g < (ZC_CAP >> 6)) {
      // compact path: thread t owns token t -> conflict-free LDS writes
      const int t = tid & 63, seg = tid >> 6;      // seg 0..3 (64 d's each)
      const int idx = g * 64 + t;
      const float* src = zc + (size_t)(idx < c ? idx : c - 1) * 256 + seg * 64;
      #pragma unroll
      for (int r = 0; r < 16; ++r) {
        f32x4 v = *(const f32x4*)(src + r * 4);
        const int d = seg * 64 + r * 4;
        zs[(d + 0) * 64 + t] = v[0];
        zs[(d + 1) * 64 + t] = v[1];
        zs[(d + 2) * 64 + t] = v[2];
        zs[(d + 3) * 64 + t] = v[3];
      }
    } else {
      // overflow fallback: scattered reads from z
      const int t = tid & 63, dq = tid >> 6;       // dq 0..3
      const int idx = g * 64 + t;
      const int n = list[idx < c ? idx : c - 1];
      #pragma unroll 4
      for (int dd = 0; dd < 64; ++dd) {
        const int d = dq * 64 + dd;
        zs[d * 64 + t] = z[(size_t)d * N_TOK + n];
      }
    }
    __syncthreads();

    unsigned long long lmin[4] = {~0ULL, ~0ULL, ~0ULL, ~0ULL};
    #pragma unroll
    for (int k0 = 0; k0 < SLABW; k0 += 64) {
      const f32x4* er[4]; float eqv[4];
      #pragma unroll
      for (int j = 0; j < 4; ++j) {
        int k = slab + k0 + ty + 16 * j;
        er[j] = (const f32x4*)(e + (size_t)k * D_DIM);
        eqv[j] = esq[k];
      }
      float acc[4][4];
      #pragma unroll
      for (int i = 0; i < 4; ++i)
        #pragma unroll
        for (int j = 0; j < 4; ++j) acc[i][j] = 0.f;
      #pragma unroll 4
      for (int d4 = 0; d4 < D_DIM / 4; ++d4) {
        f32x4 ev[4];
        #pragma unroll
        for (int j = 0; j < 4; ++j) ev[j] = er[j][d4];
        #pragma unroll
        for (int dd = 0; dd < 4; ++dd) {
          float zv[4];
          #pragma unroll
          for (int i = 0; i < 4; ++i) zv[i] = zs[(d4 * 4 + dd) * 64 + tx + 16 * i];
          #pragma unroll
          for (int i = 0; i < 4; ++i)
            #pragma unroll
            for (int j = 0; j < 4; ++j) acc[i][j] += zv[i] * ev[j][dd];
        }
      }
      #pragma unroll
      for (int j = 0; j < 4; ++j) {
        const int k = slab + k0 + ty + 16 * j;
        #pragma unroll
        for (int i = 0; i < 4; ++i) {
          float s = eqv[j] - 2.0f * acc[i][j] + 1024.0f;   // bias > 0 for packing
          unsigned long long p =
              ((unsigned long long)__float_as_uint(s) << 32) | (unsigned)k;
          lmin[i] = (p < lmin[i]) ? p : lmin[i];
        }
      }
    }
    #pragma unroll
    for (int i = 0; i < 4; ++i) red[ty * 64 + tx + 16 * i] = lmin[i];
    __syncthreads();
    if (tid < 64) {
      unsigned long long m = red[tid];
      #pragma unroll
      for (int t = 1; t < 16; ++t) {
        unsigned long long v = red[t * 64 + tid];
        m = (v < m) ? v : m;
      }
      const int idx = g * 64 + tid;
      const int n = list[idx < c ? idx : c - 1];
      atomicMin(&fixb[n], m);
    }
    // ---- completion: last item of this group writes outputs ----
    __threadfence();
    __syncthreads();
    if (tid == 0) lastflag = (atomicAdd(&gdone[g], 1) == SLABS - 1) ? 1 : 0;
    __syncthreads();
    if (lastflag) {
      if (tid < 64) {
        const int idx = g * 64 + tid;
        int kres = -1, n = -1;
        if (idx < c) {
          n = list[idx];
          unsigned long long mv = atomicMin(&fixb[n], 0xFFFFFFFFFFFFFFFFULL);
          kres = (int)(unsigned)(mv & 0xFFFFFFFFu);
          out[(size_t)D_DIM * N_TOK + n] = (float)kres;
        }
        fk[tid] = kres; fn[tid] = n;
      }
      __syncthreads();
      {
        const int t = tid & 63, dq = tid >> 6;
        const int kres = fk[t];
        if (kres >= 0) {
          const int n = fn[t];
          const float* row = e + (size_t)kres * D_DIM;
          #pragma unroll 4
          for (int dd = 0; dd < 64; ++dd) {
            const int d = dq * 64 + dd;
            out[(size_t)d * N_TOK + n] = row[d];
          }
        }
      }
    }
  }
}

// ======================= fallback (round-1 fp32 path) =======================
__global__ __launch_bounds__(256) void esq_kernel(const float* __restrict__ e,
                                                  float* __restrict__ esq) {
  const int wave = threadIdx.x >> 6, lane = threadIdx.x & 63;
  const int k = blockIdx.x * 4 + wave;
  const float4* row = (const float4*)(e + (size_t)k * D_DIM);
  float4 v = row[lane];
  float s = v.x*v.x + v.y*v.y + v.z*v.z + v.w*v.w;
  #pragma unroll
  for (int off = 32; off > 0; off >>= 1) s += __shfl_down(s, off, 64);
  if (lane == 0) esq[k] = s;
}

__global__ __launch_bounds__(256) void vq_kernel(const float* __restrict__ z,
                                                 const float* __restrict__ e,
                                                 const float* __restrict__ esq,
                                                 float* __restrict__ out) {
  __shared__ float zs[D_DIM][64];
  const int tid = threadIdx.x, tx = tid & 15, ty = tid >> 4;
  const int n0 = blockIdx.x * 64;
  {
    const int c = tid & 63, d0 = tid >> 6;
    #pragma unroll 4
    for (int d = d0; d < D_DIM; d += 4) zs[d][c] = z[(size_t)d * N_TOK + n0 + c];
  }
  __syncthreads();
  float bestv[4] = {3.4e38f,3.4e38f,3.4e38f,3.4e38f};
  int   besti[4] = {0,0,0,0};
  for (int k0 = 0; k0 < K_CB; k0 += 64) {
    const float4* er[4]; float eqv[4];
    #pragma unroll
    for (int j = 0; j < 4; ++j) {
      int k = k0 + ty + 16 * j;
      er[j] = (const float4*)(e + (size_t)k * D_DIM);
      eqv[j] = esq[k];
    }
    float acc[4][4];
    #pragma unroll
    for (int i = 0; i < 4; ++i)
      #pragma unroll
      for (int j = 0; j < 4; ++j) acc[i][j] = 0.f;
    #pragma unroll 4
    for (int d4 = 0; d4 < D_DIM/4; ++d4) {
      float4 ev[4];
      #pragma unroll
      for (int j = 0; j < 4; ++j) ev[j] = er[j][d4];
      #pragma unroll
      for (int dd = 0; dd < 4; ++dd) {
        float zv[4];
        #pragma unroll
        for (int i = 0; i < 4; ++i) zv[i] = zs[d4*4+dd][tx + 16*i];
        #pragma unroll
        for (int i = 0; i < 4; ++i)
          #pragma unroll
          for (int j = 0; j < 4; ++j) acc[i][j] += zv[i] * ((const float*)&ev[j])[dd];
      }
    }
    #pragma unroll
    for (int j = 0; j < 4; ++j) {
      int k = k0 + ty + 16 * j;
      #pragma unroll
      for (int i = 0; i < 4; ++i) {
        float s = eqv[j] - 2.0f * acc[i][j];
        if (s < bestv[i]) { bestv[i] = s; besti[i] = k; }
      }
    }
  }
  __syncthreads();
  float* lds = &zs[0][0];
  float* vred = lds; int* ired = (int*)lds + 1024; int* fin = (int*)lds + 2048;
  #pragma unroll
  for (int i = 0; i < 4; ++i) {
    int l = tx + 16 * i;
    vred[ty * 64 + l] = bestv[i]; ired[ty * 64 + l] = besti[i];
  }
  __syncthreads();
  if (tid < 64) {
    float bv = vred[tid]; int bi = ired[tid];
    #pragma unroll
    for (int t = 1; t < 16; ++t) {
      float v = vred[t*64+tid]; int ix = ired[t*64+tid];
      if (v < bv || (v == bv && ix < bi)) { bv = v; bi = ix; }
    }
    fin[tid] = bi;
    out[(size_t)D_DIM * N_TOK + n0 + tid] = (float)bi;
  }
  __syncthreads();
  {
    const int l = tid & 63, d0 = tid >> 6;
    const int kk = fin[l];
    const float* row = e + (size_t)kk * D_DIM;
    #pragma unroll 4
    for (int d = d0; d < D_DIM; d += 4) out[(size_t)d * N_TOK + n0 + l] = row[d];
  }
}

extern "C" void kernel_launch(void* const* d_in, const int* in_sizes, int n_in,
                              void* d_out, int out_size, void* d_ws, size_t ws_size,
                              hipStream_t stream) {
  const float* z = (const float*)d_in[0];
  const float* e = (const float*)d_in[1];
  float* out = (float*)d_out;
  char* ws = (char*)d_ws;

  if (ws_size >= WS_NEED) {
    float* esq = (float*)(ws + OFF_ESQ);
    int* cnt = (int*)(ws + OFF_CNT);
    int* gdone = (int*)(ws + OFF_GDONE);
    int* list = (int*)(ws + OFF_LIST);
    unsigned long long* fixb = (unsigned long long*)(ws + OFF_FIXB);
    short* eht = (short*)(ws + OFF_EHT);
    float* zc = (float*)(ws + OFF_ZC);

    (void)hipFuncSetAttribute((const void*)vq_main_kernel,
                              hipFuncAttributeMaxDynamicSharedMemorySize, SMEM_MAIN);

    eprep_kernel<<<128, 256, 0, stream>>>(e, eht, esq, cnt, gdone);
    vq_main_kernel<<<256, 1024, SMEM_MAIN, stream>>>(z, e, esq, eht,
                                                     out, cnt, list, fixb, zc);
    rescan_kernel<<<512, 256, 0, stream>>>(z, zc, e, esq, cnt, list, fixb, gdone, out);
  } else {
    float* esq = (float*)(ws);
    esq_kernel<<<K_CB / 4, 256, 0, stream>>>(e, esq);
    vq_kernel<<<N_TOK / 64, 256, 0, stream>>>(z, e, esq, out);
  }
}